// Round 1
// baseline (279.618 us; speedup 1.0000x reference)
//
#include <hip/hip_runtime.h>

// BalancedCELoss: loss = -mean( t==1 ? 2*log(p) : 1*log1p(-p) ), N = 33554432.
// Memory-bound reduction: 256 MB traffic -> ~41 us roofline at 6.3 TB/s.

#define W0 1.0f
#define W1 2.0f

__global__ __launch_bounds__(256) void bce_reduce_kernel(
    const float* __restrict__ p, const int* __restrict__ t,
    float* __restrict__ partial, int n4) {
  const float4* p4 = (const float4*)p;
  const int4*   t4 = (const int4*)t;

  float acc = 0.f;
  int idx    = blockIdx.x * blockDim.x + threadIdx.x;
  int stride = gridDim.x * blockDim.x;

  for (int i = idx; i < n4; i += stride) {
    float4 pv = p4[i];
    int4   tv = t4[i];
    // single log per element: x = t ? p : 1-p ; w = t ? W1 : W0
    float x0 = tv.x ? pv.x : 1.0f - pv.x;
    float x1 = tv.y ? pv.y : 1.0f - pv.y;
    float x2 = tv.z ? pv.z : 1.0f - pv.z;
    float x3 = tv.w ? pv.w : 1.0f - pv.w;
    float w0 = tv.x ? W1 : W0;
    float w1 = tv.y ? W1 : W0;
    float w2 = tv.z ? W1 : W0;
    float w3 = tv.w ? W1 : W0;
    acc += w0 * __logf(x0);
    acc += w1 * __logf(x1);
    acc += w2 * __logf(x2);
    acc += w3 * __logf(x3);
  }

  // wave-64 reduce
  #pragma unroll
  for (int off = 32; off > 0; off >>= 1)
    acc += __shfl_down(acc, off, 64);

  __shared__ float s[4];  // 256 threads = 4 waves
  int wave = threadIdx.x >> 6;
  if ((threadIdx.x & 63) == 0) s[wave] = acc;
  __syncthreads();

  if (threadIdx.x == 0) {
    float b = s[0] + s[1] + s[2] + s[3];
    atomicAdd(partial, b);  // device-scope by default (cross-XCD safe)
  }
}

__global__ void bce_finalize_kernel(const float* __restrict__ partial,
                                    float* __restrict__ out, float inv_n) {
  out[0] = -partial[0] * inv_n;
}

extern "C" void kernel_launch(void* const* d_in, const int* in_sizes, int n_in,
                              void* d_out, int out_size, void* d_ws, size_t ws_size,
                              hipStream_t stream) {
  const float* p = (const float*)d_in[0];
  const int*   t = (const int*)d_in[1];
  float* out = (float*)d_out;
  float* ws  = (float*)d_ws;

  int n  = in_sizes[0];
  int n4 = n / 4;  // N = 33554432 is divisible by 4

  // d_ws is poisoned to 0xAA before every timed launch -> zero the accumulator.
  hipMemsetAsync(ws, 0, sizeof(float), stream);

  const int block = 256;
  const int grid  = 2048;  // 256 CU x 8 blocks, grid-stride covers the rest
  bce_reduce_kernel<<<grid, block, 0, stream>>>(p, t, ws, n4);
  bce_finalize_kernel<<<1, 1, 0, stream>>>(ws, out, 1.0f / (float)n);
}

// Round 2
// 278.153 us; speedup vs baseline: 1.0053x; 1.0053x over previous
//
#include <hip/hip_runtime.h>

// BalancedCELoss: loss = -mean( t==1 ? 2*log(p) : 1*log1p(-p) ), N = 33554432.
// Memory-bound reduction: 256 MB traffic -> ~41 us roofline at 6.3 TB/s.
// R1 was latency-bound (2 loads in flight/wave, 12 VGPRs, 1.28 TB/s).
// R2: x4 unroll, 8 loads in flight per wave before any consume.

#define W0 1.0f
#define W1 2.0f

#define GRID  2048
#define BLOCK 256

__global__ __launch_bounds__(BLOCK) void bce_reduce_kernel(
    const float* __restrict__ p, const int* __restrict__ t,
    float* __restrict__ partial, int n4) {
  const float4* p4 = (const float4*)p;
  const int4*   t4 = (const int4*)t;

  const int idx    = blockIdx.x * BLOCK + threadIdx.x;
  const int stride = GRID * BLOCK;

  float acc = 0.f;

  // main unrolled-by-4 loop: issue all 8 loads, then compute.
  int i = idx;
  for (; i + 3 * stride < n4; i += 4 * stride) {
    float4 pv0 = p4[i + 0 * stride];
    float4 pv1 = p4[i + 1 * stride];
    float4 pv2 = p4[i + 2 * stride];
    float4 pv3 = p4[i + 3 * stride];
    int4   tv0 = t4[i + 0 * stride];
    int4   tv1 = t4[i + 1 * stride];
    int4   tv2 = t4[i + 2 * stride];
    int4   tv3 = t4[i + 3 * stride];

    float a0 = 0.f, a1 = 0.f, a2 = 0.f, a3 = 0.f;
    // x = t ? p : 1-p ; w = t ? W1 : W0 ; acc += w*log(x)
    a0 += (tv0.x ? W1 : W0) * __logf(tv0.x ? pv0.x : 1.0f - pv0.x);
    a0 += (tv0.y ? W1 : W0) * __logf(tv0.y ? pv0.y : 1.0f - pv0.y);
    a0 += (tv0.z ? W1 : W0) * __logf(tv0.z ? pv0.z : 1.0f - pv0.z);
    a0 += (tv0.w ? W1 : W0) * __logf(tv0.w ? pv0.w : 1.0f - pv0.w);
    a1 += (tv1.x ? W1 : W0) * __logf(tv1.x ? pv1.x : 1.0f - pv1.x);
    a1 += (tv1.y ? W1 : W0) * __logf(tv1.y ? pv1.y : 1.0f - pv1.y);
    a1 += (tv1.z ? W1 : W0) * __logf(tv1.z ? pv1.z : 1.0f - pv1.z);
    a1 += (tv1.w ? W1 : W0) * __logf(tv1.w ? pv1.w : 1.0f - pv1.w);
    a2 += (tv2.x ? W1 : W0) * __logf(tv2.x ? pv2.x : 1.0f - pv2.x);
    a2 += (tv2.y ? W1 : W0) * __logf(tv2.y ? pv2.y : 1.0f - pv2.y);
    a2 += (tv2.z ? W1 : W0) * __logf(tv2.z ? pv2.z : 1.0f - pv2.z);
    a2 += (tv2.w ? W1 : W0) * __logf(tv2.w ? pv2.w : 1.0f - pv2.w);
    a3 += (tv3.x ? W1 : W0) * __logf(tv3.x ? pv3.x : 1.0f - pv3.x);
    a3 += (tv3.y ? W1 : W0) * __logf(tv3.y ? pv3.y : 1.0f - pv3.y);
    a3 += (tv3.z ? W1 : W0) * __logf(tv3.z ? pv3.z : 1.0f - pv3.z);
    a3 += (tv3.w ? W1 : W0) * __logf(tv3.w ? pv3.w : 1.0f - pv3.w);
    acc += (a0 + a1) + (a2 + a3);
  }
  // tail (not taken for N=32M with this grid, but keep it correct)
  for (; i < n4; i += stride) {
    float4 pv = p4[i];
    int4   tv = t4[i];
    acc += (tv.x ? W1 : W0) * __logf(tv.x ? pv.x : 1.0f - pv.x);
    acc += (tv.y ? W1 : W0) * __logf(tv.y ? pv.y : 1.0f - pv.y);
    acc += (tv.z ? W1 : W0) * __logf(tv.z ? pv.z : 1.0f - pv.z);
    acc += (tv.w ? W1 : W0) * __logf(tv.w ? pv.w : 1.0f - pv.w);
  }

  // wave-64 reduce
  #pragma unroll
  for (int off = 32; off > 0; off >>= 1)
    acc += __shfl_down(acc, off, 64);

  __shared__ float s[BLOCK / 64];
  const int wave = threadIdx.x >> 6;
  if ((threadIdx.x & 63) == 0) s[wave] = acc;
  __syncthreads();

  if (threadIdx.x == 0) {
    partial[blockIdx.x] = (s[0] + s[1]) + (s[2] + s[3]);  // plain store, no atomic
  }
}

// Reduce GRID partials -> out = -sum/N. One block of 256 threads.
__global__ __launch_bounds__(256) void bce_finalize_kernel(
    const float* __restrict__ partial, float* __restrict__ out, float inv_n) {
  float acc = 0.f;
  for (int i = threadIdx.x; i < GRID; i += 256)
    acc += partial[i];
  #pragma unroll
  for (int off = 32; off > 0; off >>= 1)
    acc += __shfl_down(acc, off, 64);
  __shared__ float s[4];
  const int wave = threadIdx.x >> 6;
  if ((threadIdx.x & 63) == 0) s[wave] = acc;
  __syncthreads();
  if (threadIdx.x == 0)
    out[0] = -((s[0] + s[1]) + (s[2] + s[3])) * inv_n;
}

extern "C" void kernel_launch(void* const* d_in, const int* in_sizes, int n_in,
                              void* d_out, int out_size, void* d_ws, size_t ws_size,
                              hipStream_t stream) {
  const float* p = (const float*)d_in[0];
  const int*   t = (const int*)d_in[1];
  float* out = (float*)d_out;
  float* ws  = (float*)d_ws;  // GRID floats of per-block partials (overwritten, no init needed)

  const int n  = in_sizes[0];
  const int n4 = n / 4;

  bce_reduce_kernel<<<GRID, BLOCK, 0, stream>>>(p, t, ws, n4);
  bce_finalize_kernel<<<1, 256, 0, stream>>>(ws, out, 1.0f / (float)n);
}